// Round 10
// baseline (403.871 us; speedup 1.0000x reference)
//
#include <hip/hip_runtime.h>
#include <hip/hip_bf16.h>
#include <stdint.h>

typedef __attribute__((ext_vector_type(4))) float f32x4;
typedef __attribute__((ext_vector_type(8))) short s16x8;
typedef __attribute__((ext_vector_type(4))) short s16x4;

// XOR-swizzle of 16B-granule index within a 128B row (involution on low 3 bits)
#define SWZ(g, row) ((((g) & ~7) | (((g) ^ ((row) & 7)) & 7)))

__device__ __forceinline__ unsigned short f2bf(float f) {
  unsigned u = __builtin_bit_cast(unsigned, f);
  u += 0x7fffu + ((u >> 16) & 1u);   // round-to-nearest-even
  return (unsigned short)(u >> 16);
}

__device__ __forceinline__ void gld16(const void* g, void* l) {
  __builtin_amdgcn_global_load_lds(
      (const __attribute__((address_space(1))) void*)g,
      (__attribute__((address_space(3))) void*)l, 16, 0, 0);
}

// ---------------------------------------------------------------- fused convert
__global__ void cvt_all(const float* __restrict__ x, const float* __restrict__ qkvw,
                        const float* __restrict__ ow, unsigned short* __restrict__ X16,
                        unsigned short* __restrict__ W16, unsigned short* __restrict__ OW16) {
  int i = blockIdx.x * blockDim.x + threadIdx.x;
  const float* src; unsigned short* dst; int off;
  if (i < 2097152)      { src = x;    dst = X16;  off = i; }
  else if (i < 5242880) { src = qkvw; dst = W16;  off = i - 2097152; }
  else                  { src = ow;   dst = OW16; off = i - 5242880; }
  float4 v = ((const float4*)src)[off];
  s16x4 o;
  o[0] = (short)f2bf(v.x); o[1] = (short)f2bf(v.y);
  o[2] = (short)f2bf(v.z); o[3] = (short)f2bf(v.w);
  ((s16x4*)dst)[off] = o;
}

// ---------------------------------------------------------------- shared phase machinery
#define PH_PRE \
  __builtin_amdgcn_s_barrier(); \
  asm volatile("s_waitcnt lgkmcnt(0)" ::: "memory"); \
  __builtin_amdgcn_sched_barrier(0); \
  __builtin_amdgcn_s_setprio(1);

#define PH_POST_N \
  __builtin_amdgcn_s_setprio(0); \
  __builtin_amdgcn_s_barrier();

#define PH_POST_W0 \
  __builtin_amdgcn_s_setprio(0); \
  asm volatile("s_waitcnt vmcnt(0)" ::: "memory"); \
  __builtin_amdgcn_s_barrier();

#define PH_POST_W2 \
  __builtin_amdgcn_s_setprio(0); \
  asm volatile("s_waitcnt vmcnt(2)" ::: "memory"); \
  __builtin_amdgcn_s_barrier();

#define PH_POST_W3 \
  __builtin_amdgcn_s_setprio(0); \
  asm volatile("s_waitcnt vmcnt(3)" ::: "memory"); \
  __builtin_amdgcn_s_barrier();

#define RDA(KS) \
  _Pragma("unroll") for (int j = 0; j < 4; ++j) { \
    const int ra = wm * 64 + j * 16 + lg; \
    av[j] = *(const s16x8*)(sA + ra * 128 + (SWZ(4 * (KS) + hg, ra) << 4)); }

// ---------------------------------------------------------------- QKV GEMM, 128x384 tile
#define STG_A(DST, ORG, KT) \
  _Pragma("unroll") for (int rr = 0; rr < 2; ++rr) { \
    const int G = rr * 512 + tid; const int row = G >> 3, g = G & 7; \
    gld16((const char*)((ORG) + (size_t)row * 2048 + (size_t)(KT) * 64) + (SWZ(g, row) << 4), \
          (DST) + rr * 8192 + tid * 16); }

#define STG_B2(DST, ORG, KT, R0) \
  _Pragma("unroll") for (int rr = (R0); rr < (R0) + 2; ++rr) { \
    const int G = rr * 512 + tid; const int row = G >> 3, g = G & 7; \
    gld16((const char*)((ORG) + (size_t)row * 2048 + (size_t)(KT) * 64) + (SWZ(g, row) << 4), \
          (DST) + rr * 8192 + tid * 16); }

#define RDB(KS, CH) \
  _Pragma("unroll") for (int b = 0; b < 3; ++b) { \
    const int bb = (CH) * 3 + b; \
    const int cb = (bb >> 1) * 128 + wn * 16 + (bb & 1) * 64 + lg; \
    bv[b] = *(const s16x8*)(sB + cb * 128 + (SWZ(4 * (KS) + hg, cb) << 4)); }

#define MM12(CH) \
  _Pragma("unroll") for (int j = 0; j < 4; ++j) \
    _Pragma("unroll") for (int b = 0; b < 3; ++b) \
      acc[j][(CH) * 3 + b] = __builtin_amdgcn_mfma_f32_16x16x32_bf16( \
          av[j], bv[b], acc[j][(CH) * 3 + b], 0, 0, 0);

__global__ __launch_bounds__(512, 1) void gemm_qkv_384(
    const unsigned short* __restrict__ A,
    const unsigned short* __restrict__ Bt,
    const float* __restrict__ cosT, const float* __restrict__ sinT,
    unsigned short* __restrict__ qOut, unsigned short* __restrict__ kOut,
    unsigned short* __restrict__ vtOut)
{
  __shared__ char smem[131072];   // buf b: A @ b*65536 (16KB), B @ +16384 (48KB)
  const int tid = (int)threadIdx.x;
  const int wid = tid >> 6, l = tid & 63;
  const int lg = l & 15, hg = l >> 4;
  const int wm = wid >> 2, wn = wid & 3;
  const int s = ((int)blockIdx.x & 7) * 64 + ((int)blockIdx.x >> 3);
  const int bm0 = (s & 31) * 128, bn0 = (s >> 5) * 384;

  const unsigned short* Aorg = A + (size_t)bm0 * 2048;
  const unsigned short* Borg = Bt + (size_t)bn0 * 2048;

  f32x4 acc[4][6] = {};

  // prologue: all 8 loads of tile 0 (order A0,A1,B0..B5); first 5 must land
  STG_A(smem + 0, Aorg, 0)
  STG_B2(smem + 16384, Borg, 0, 0)
  STG_B2(smem + 16384, Borg, 0, 2)
  STG_B2(smem + 16384, Borg, 0, 4)
  asm volatile("s_waitcnt vmcnt(3)" ::: "memory");
  __builtin_amdgcn_s_barrier();

  for (int t = 0; t < 31; ++t) {
    const char* sA = smem + (t & 1) * 65536;
    const char* sB = sA + 16384;
    char* dA = smem + ((t & 1) ^ 1) * 65536;
    char* dB = dA + 16384;
    s16x8 av[4], bv[3];
    RDA(0) RDB(0, 0) STG_A(dA, Aorg, t + 1)      PH_PRE MM12(0) PH_POST_W2
    RDB(0, 1)        STG_B2(dB, Borg, t + 1, 0)  PH_PRE MM12(1) PH_POST_N
    RDA(1) RDB(1, 1) STG_B2(dB, Borg, t + 1, 2)  PH_PRE MM12(1) PH_POST_N
    RDB(1, 0)        STG_B2(dB, Borg, t + 1, 4)  PH_PRE MM12(0) PH_POST_W3
  }
  {  // tail tile t = 31 (buf 1), no issues; only full drain after phase 0
    const char* sA = smem + 65536;
    const char* sB = sA + 16384;
    s16x8 av[4], bv[3];
    RDA(0) RDB(0, 0)  PH_PRE MM12(0) PH_POST_W0
    RDB(0, 1)         PH_PRE MM12(1) PH_POST_N
    RDA(1) RDB(1, 1)  PH_PRE MM12(1) PH_POST_N
    RDB(1, 0)         PH_PRE MM12(0)
    __builtin_amdgcn_s_setprio(0);
  }

  // ---- epilogue: rotary for q/k head-groups, transposed-V for v head-groups
  #pragma unroll
  for (int j = 0; j < 4; ++j) {
    const int grow0 = bm0 + wm * 64 + j * 16 + hg * 4;
    const int b_ = grow0 >> 11;
    #pragma unroll
    for (int cg = 0; cg < 3; ++cg) {
      const int og = (bn0 >> 7) + cg;
      const int tt = og >> 4, h = og & 15;
      const int d = wn * 16 + lg;
      if (tt < 2) {
        unsigned short* dst = (tt == 0) ? qOut : kOut;
        #pragma unroll
        for (int r = 0; r < 4; ++r) {
          const int gr = grow0 + r;
          const int s1 = gr & 2047;
          const float x1 = acc[j][cg * 2 + 0][r];
          const float x2 = acc[j][cg * 2 + 1][r];
          const float cv = cosT[s1 * 64 + d];
          const float sv = sinT[s1 * 64 + d];
          const size_t base = (((size_t)b_ * 16 + h) * 2048 + s1) * 128;
          dst[base + d]      = f2bf(x1 * cv - x2 * sv);
          dst[base + d + 64] = f2bf(x2 * cv + x1 * sv);
        }
      } else {
        const int s0 = grow0 & 2047;
        s16x4 p1, p2;
        #pragma unroll
        for (int r = 0; r < 4; ++r) {
          p1[r] = (short)f2bf(acc[j][cg * 2 + 0][r]);
          p2[r] = (short)f2bf(acc[j][cg * 2 + 1][r]);
        }
        *(s16x4*)(vtOut + (((size_t)b_ * 16 + h) * 128 + d)      * 2048 + s0) = p1;
        *(s16x4*)(vtOut + (((size_t)b_ * 16 + h) * 128 + d + 64) * 2048 + s0) = p2;
      }
    }
  }
}

// ---------------------------------------------------------------- out-proj GEMM, 128x256
#define RDBO(KS, CH) \
  _Pragma("unroll") for (int b = 0; b < 2; ++b) { \
    const int cb = ((CH) * 2 + b) * 64 + wn * 16 + lg; \
    bv[b] = *(const s16x8*)(sB + cb * 128 + (SWZ(4 * (KS) + hg, cb) << 4)); }

#define MMO(CH) \
  _Pragma("unroll") for (int j = 0; j < 4; ++j) \
    _Pragma("unroll") for (int b = 0; b < 2; ++b) \
      acc[j][(CH) * 2 + b] = __builtin_amdgcn_mfma_f32_16x16x32_bf16( \
          av[j], bv[b], acc[j][(CH) * 2 + b], 0, 0, 0);

__global__ __launch_bounds__(512, 1) void gemm_op_256(
    const unsigned short* __restrict__ A,
    const unsigned short* __restrict__ Bt,
    float* __restrict__ C)
{
  __shared__ char smem[98304];   // buf b @ b*49152: A 16KB, B 32KB
  const int tid = (int)threadIdx.x;
  const int wid = tid >> 6, l = tid & 63;
  const int lg = l & 15, hg = l >> 4;
  const int wm = wid >> 2, wn = wid & 3;
  const int s = ((int)blockIdx.x & 7) * 32 + ((int)blockIdx.x >> 3);
  const int bm0 = (s & 31) * 128, bn0 = (s >> 5) * 256;

  const unsigned short* Aorg = A + (size_t)bm0 * 2048;
  const unsigned short* Borg = Bt + (size_t)bn0 * 2048;

  f32x4 acc[4][4] = {};

  STG_A(smem + 0, Aorg, 0)
  STG_B2(smem + 16384, Borg, 0, 0)
  STG_B2(smem + 16384, Borg, 0, 2)
  asm volatile("s_waitcnt vmcnt(2)" ::: "memory");
  __builtin_amdgcn_s_barrier();

  for (int t = 0; t < 31; ++t) {
    const char* sA = smem + (t & 1) * 49152;
    const char* sB = sA + 16384;
    char* dA = smem + ((t & 1) ^ 1) * 49152;
    char* dB = dA + 16384;
    s16x8 av[4], bv[2];
    RDA(0) RDBO(0, 0) STG_A(dA, Aorg, t + 1)      PH_PRE MMO(0) PH_POST_W2
    RDBO(0, 1)        STG_B2(dB, Borg, t + 1, 0)  PH_PRE MMO(1) PH_POST_N
    RDA(1) RDBO(1, 1) STG_B2(dB, Borg, t + 1, 2)  PH_PRE MMO(1) PH_POST_N
    RDBO(1, 0)                                    PH_PRE MMO(0) PH_POST_W2
  }
  {
    const char* sA = smem + 49152;
    const char* sB = sA + 16384;
    s16x8 av[4], bv[2];
    RDA(0) RDBO(0, 0)  PH_PRE MMO(0) PH_POST_W0
    RDBO(0, 1)         PH_PRE MMO(1) PH_POST_N
    RDA(1) RDBO(1, 1)  PH_PRE MMO(1) PH_POST_N
    RDBO(1, 0)         PH_PRE MMO(0)
    __builtin_amdgcn_s_setprio(0);
  }

  #pragma unroll
  for (int j = 0; j < 4; ++j) {
    const int row0 = bm0 + wm * 64 + j * 16 + hg * 4;
    #pragma unroll
    for (int b = 0; b < 4; ++b) {
      const int col = bn0 + b * 64 + wn * 16 + lg;
      #pragma unroll
      for (int r = 0; r < 4; ++r)
        C[(size_t)(row0 + r) * 2048 + col] = acc[j][b][r];
    }
  }
}

// ---------------------------------------------------------------- flash attention (r10)
// 512 blocks = 32 bh x 16 qt-pairs; 2 blocks/CU (LDS 80KB). Per block: 128 q-rows,
// 4 waves x 32 q (two 16-row halves A/B sharing K/V fragment reads). KV tiles 64,
// double-buffered staging w/ counted vmcnt(8). qt pairing (j, 15-j) -> 34 tiles/CU.
#define ASTG(BB, KV0) \
  _Pragma("unroll") for (int i = 0; i < 4; ++i) { \
    const int G = w * 256 + i * 64 + l; \
    const int rk = G >> 4, gk = G & 15; \
    gld16((const char*)(Kp + qkBase + (size_t)((KV0) + rk) * 128) + (SWZ(gk, rk) << 4), \
          &sK[BB][w * 4096 + i * 1024]); \
    const int rv = G >> 3, gv = G & 7; \
    gld16((const char*)(Vt + qkBase + (size_t)rv * 2048 + (KV0)) + (SWZ(gv, rv) << 4), \
          &sV[BB][w * 4096 + i * 1024]); \
  }

// softmax + P-store for one half; flat macro (no lambdas — r2 spill lesson)
#define SMAX(SS, MM, LL, AO, QI, PB, DG) { \
  float mt = -1e30f; \
  _Pragma("unroll") for (int kf = 0; kf < 4; ++kf) \
    _Pragma("unroll") for (int r = 0; r < 4; ++r) { \
      float sv_ = SS[kf][r]; \
      if (DG) { \
        const int jj = kv0 + kf * 16 + hg * 4 + r; \
        sv_ = (jj > (QI)) ? -1e30f : sv_; \
        SS[kf][r] = sv_; \
      } \
      mt = fmaxf(mt, sv_); \
    } \
  mt = fmaxf(mt, __shfl_xor(mt, 16)); \
  mt = fmaxf(mt, __shfl_xor(mt, 32)); \
  mt *= SCALE; \
  if (!__all(mt - MM <= 8.0f)) { \
    const float mnew = fmaxf(MM, mt); \
    const float alpha = exp2f((MM - mnew) * L2E); \
    float ar[4]; \
    _Pragma("unroll") for (int r = 0; r < 4; ++r) ar[r] = __shfl(alpha, hg * 4 + r); \
    _Pragma("unroll") for (int f = 0; f < 8; ++f) \
      _Pragma("unroll") for (int r = 0; r < 4; ++r) AO[f][r] *= ar[r]; \
    LL *= alpha; \
    MM = mnew; \
  } \
  { const float mL = MM * L2E; \
    float ls = 0.f; \
    _Pragma("unroll") for (int kf = 0; kf < 4; ++kf) { \
      s16x4 pk; \
      _Pragma("unroll") for (int r = 0; r < 4; ++r) { \
        const float e = exp2f(SS[kf][r] * CS - mL); \
        ls += e; \
        pk[r] = (short)f2bf(e); \
      } \
      const int j0 = kf * 16 + hg * 4; \
      *(s16x4*)((PB) + lg * 128 + (SWZ(j0 >> 3, lg) << 4) + ((j0 * 2) & 15)) = pk; \
    } \
    ls += __shfl_xor(ls, 16); \
    ls += __shfl_xor(ls, 32); \
    LL += ls; } }

__global__ __launch_bounds__(256) void attn_fwd(
    const unsigned short* __restrict__ Qp, const unsigned short* __restrict__ Kp,
    const unsigned short* __restrict__ Vt, unsigned short* __restrict__ AO)
{
  __shared__ char sK[2][16384];   // [64][128] bf16, swizzled granules
  __shared__ char sV[2][16384];   // [128][64] bf16 (Vt tile), swizzled
  __shared__ char sP[16384];      // wave w: half A @ w*4096, half B @ +2048

  const int tid = (int)threadIdx.x, w = tid >> 6, l = tid & 63;
  const int lg = l & 15, hg = l >> 4;
  const int bid = (int)blockIdx.x;
  const int p = bid >> 8, c = bid & 255;
  const int j = c >> 5, bh = c & 31;
  const int qt = p ? (15 - j) : j;               // CU pairing: 34 tiles/CU
  const size_t qkBase = (size_t)bh * 2048 * 128; // also Vt head base
  const int qw0 = qt * 128 + w * 32;
  const int qiA = qw0 + lg, qiB = qw0 + 16 + lg;

  char* const pbA = sP + w * 4096;
  char* const pbB = pbA + 2048;

  // Q fragments: lane holds q-row (l&15) of its half, feature 32*ks + 8*hg
  s16x8 qfA[4], qfB[4];
  #pragma unroll
  for (int ks = 0; ks < 4; ++ks) {
    qfA[ks] = *(const s16x8*)(Qp + qkBase + (size_t)(qw0 + lg) * 128 + ks * 32 + hg * 8);
    qfB[ks] = *(const s16x8*)(Qp + qkBase + (size_t)(qw0 + 16 + lg) * 128 + ks * 32 + hg * 8);
  }

  f32x4 aoA[8] = {}, aoB[8] = {};
  float mA = -1e30f, lA = 0.f, mB = -1e30f, lB = 0.f;
  const float SCALE = 0.08838834764831845f;   // 1/sqrt(128)
  const float L2E = 1.4426950408889634f;
  const float CS = SCALE * L2E;

  const int nkv = 2 * qt + 2;

  // prologue: stage tiles 0 and 1 (nkv >= 2 always)
  ASTG(0, 0)
  ASTG(1, 64)
  asm volatile("s_waitcnt vmcnt(8)" ::: "memory");   // tile 0 landed
  __builtin_amdgcn_s_barrier();

  for (int kv = 0; kv < nkv; ++kv) {
    const int cur = kv & 1;
    const int kv0 = kv * 64;
    const char* cK = sK[cur];
    const char* cV = sV[cur];
    const bool actB = (kv0 <= qw0 + 31);
    const bool actA = (kv0 <= qw0 + 15);

    if (actB) {
      // ---- QK^T (swapped): K-frags shared between halves
      f32x4 sSA[4] = {}, sSB[4] = {};
      #pragma unroll
      for (int ks = 0; ks < 4; ++ks)
        #pragma unroll
        for (int kf = 0; kf < 4; ++kf) {
          const int row = kf * 16 + lg;
          s16x8 kfrag = *(const s16x8*)(cK + row * 256 + (SWZ(4 * ks + hg, row) << 4));
          sSB[kf] = __builtin_amdgcn_mfma_f32_16x16x32_bf16(kfrag, qfB[ks], sSB[kf], 0, 0, 0);
          if (actA)
            sSA[kf] = __builtin_amdgcn_mfma_f32_16x16x32_bf16(kfrag, qfA[ks], sSA[kf], 0, 0, 0);
        }

      // ---- online softmax per half (diag-only mask, folded scale, defer-max)
      const bool dgB = (kv0 + 63 > qw0 + 16);
      SMAX(sSB, mB, lB, aoB, qiB, pbB, dgB)
      if (actA) {
        const bool dgA = (kv0 + 63 > qw0);
        SMAX(sSA, mA, lA, aoA, qiA, pbA, dgA)
      }
      asm volatile("" ::: "memory");   // P writes precede P reads (in-order DS)

      // ---- PV: V-frags shared between halves
      #pragma unroll
      for (int jc = 0; jc < 2; ++jc) {
        const int gp = SWZ(hg + 4 * jc, lg);
        s16x8 paB = *(const s16x8*)(pbB + lg * 128 + (gp << 4));
        s16x8 paA;
        if (actA) paA = *(const s16x8*)(pbA + lg * 128 + (gp << 4));
        #pragma unroll
        for (int f = 0; f < 8; ++f) {
          const int rv = f * 16 + lg;
          s16x8 vb = *(const s16x8*)(cV + rv * 128 + (SWZ(hg + 4 * jc, rv) << 4));
          aoB[f] = __builtin_amdgcn_mfma_f32_16x16x32_bf16(paB, vb, aoB[f], 0, 0, 0);
          if (actA)
            aoA[f] = __builtin_amdgcn_mfma_f32_16x16x32_bf16(paA, vb, aoA[f], 0, 0, 0);
        }
      }
    }

    // ---- advance pipeline (block-uniform)
    asm volatile("s_waitcnt lgkmcnt(0)" ::: "memory");
    __builtin_amdgcn_s_barrier();                    // all waves done reading buf[cur]
    if (kv + 2 < nkv) {
      ASTG(cur, kv0 + 128)                           // refill buf[cur] with tile kv+2
      asm volatile("s_waitcnt vmcnt(8)" ::: "memory");  // tile kv+1 landed
    } else {
      asm volatile("s_waitcnt vmcnt(0)" ::: "memory");
    }
    __builtin_amdgcn_s_barrier();
  }

  // ---- normalize + store AO[b*2048+s][h*128+d] bf16 (both halves)
  const int b = bh >> 4, h = bh & 15;
  float liA[4], liB[4];
  #pragma unroll
  for (int r = 0; r < 4; ++r) {
    liA[r] = 1.0f / __shfl(lA, hg * 4 + r);
    liB[r] = 1.0f / __shfl(lB, hg * 4 + r);
  }
  #pragma unroll
  for (int f = 0; f < 8; ++f) {
    const int d = h * 128 + f * 16 + lg;
    #pragma unroll
    for (int r = 0; r < 4; ++r) {
      const int srA = qw0 + hg * 4 + r;
      const int srB = qw0 + 16 + hg * 4 + r;
      AO[((size_t)(b * 2048 + srA)) * 2048 + d] = f2bf(aoA[f][r] * liA[r]);
      AO[((size_t)(b * 2048 + srB)) * 2048 + d] = f2bf(aoB[f][r] * liB[r]);
    }
  }
}

// ---------------------------------------------------------------- launch
extern "C" void kernel_launch(void* const* d_in, const int* in_sizes, int n_in,
                              void* d_out, int out_size, void* d_ws, size_t ws_size,
                              hipStream_t stream) {
  const float* x    = (const float*)d_in[0];
  const float* qkvw = (const float*)d_in[1];
  const float* ow   = (const float*)d_in[2];
  const float* cosT = (const float*)d_in[3];
  const float* sinT = (const float*)d_in[4];
  float* out = (float*)d_out;

  unsigned short* X16  = (unsigned short*)d_ws;        // 4096x2048
  unsigned short* W16  = X16  + (size_t)8388608;       // 6144x2048
  unsigned short* OW16 = W16  + (size_t)12582912;      // 2048x2048
  unsigned short* Qp   = OW16 + (size_t)4194304;       // [2][16][2048][128]
  unsigned short* Kp   = Qp   + (size_t)8388608;
  unsigned short* Vtp  = Kp   + (size_t)8388608;       // [2][16][128][2048]
  unsigned short* AO   = Vtp  + (size_t)8388608;       // 4096x2048

  cvt_all<<<24576, 256, 0, stream>>>(x, qkvw, ow, X16, W16, OW16);

  gemm_qkv_384<<<512, 512, 0, stream>>>(X16, W16, cosT, sinT, Qp, Kp, Vtp);

  attn_fwd<<<512, 256, 0, stream>>>(Qp, Kp, Vtp, AO);

  gemm_op_256<<<256, 512, 0, stream>>>(AO, OW16, out);
}

// Round 11
// 240.224 us; speedup vs baseline: 1.6812x; 1.6812x over previous
//
#include <hip/hip_runtime.h>
#include <hip/hip_bf16.h>
#include <stdint.h>

typedef __attribute__((ext_vector_type(4))) float f32x4;
typedef __attribute__((ext_vector_type(16))) float f32x16;
typedef __attribute__((ext_vector_type(8))) short s16x8;
typedef __attribute__((ext_vector_type(4))) short s16x4;

// XOR-swizzle of 16B-granule index within a 128B row (involution on low 3 bits)
#define SWZ(g, row) ((((g) & ~7) | (((g) ^ ((row) & 7)) & 7)))
// 4-bit XOR swizzle for 256B rows (16 granules)
#define SWZ4(g, row) ((g) ^ ((row) & 15))

__device__ __forceinline__ unsigned short f2bf(float f) {
  unsigned u = __builtin_bit_cast(unsigned, f);
  u += 0x7fffu + ((u >> 16) & 1u);   // round-to-nearest-even
  return (unsigned short)(u >> 16);
}

__device__ __forceinline__ void gld16(const void* g, void* l) {
  __builtin_amdgcn_global_load_lds(
      (const __attribute__((address_space(1))) void*)g,
      (__attribute__((address_space(3))) void*)l, 16, 0, 0);
}

// ---------------------------------------------------------------- fused convert
__global__ void cvt_all(const float* __restrict__ x, const float* __restrict__ qkvw,
                        const float* __restrict__ ow, unsigned short* __restrict__ X16,
                        unsigned short* __restrict__ W16, unsigned short* __restrict__ OW16) {
  int i = blockIdx.x * blockDim.x + threadIdx.x;
  const float* src; unsigned short* dst; int off;
  if (i < 2097152)      { src = x;    dst = X16;  off = i; }
  else if (i < 5242880) { src = qkvw; dst = W16;  off = i - 2097152; }
  else                  { src = ow;   dst = OW16; off = i - 5242880; }
  float4 v = ((const float4*)src)[off];
  s16x4 o;
  o[0] = (short)f2bf(v.x); o[1] = (short)f2bf(v.y);
  o[2] = (short)f2bf(v.z); o[3] = (short)f2bf(v.w);
  ((s16x4*)dst)[off] = o;
}

// ---------------------------------------------------------------- shared phase machinery
#define PH_PRE \
  __builtin_amdgcn_s_barrier(); \
  asm volatile("s_waitcnt lgkmcnt(0)" ::: "memory"); \
  __builtin_amdgcn_sched_barrier(0); \
  __builtin_amdgcn_s_setprio(1);

#define PH_POST_N \
  __builtin_amdgcn_s_setprio(0); \
  __builtin_amdgcn_s_barrier();

#define PH_POST_W0 \
  __builtin_amdgcn_s_setprio(0); \
  asm volatile("s_waitcnt vmcnt(0)" ::: "memory"); \
  __builtin_amdgcn_s_barrier();

#define PH_POST_W2 \
  __builtin_amdgcn_s_setprio(0); \
  asm volatile("s_waitcnt vmcnt(2)" ::: "memory"); \
  __builtin_amdgcn_s_barrier();

#define PH_POST_W3 \
  __builtin_amdgcn_s_setprio(0); \
  asm volatile("s_waitcnt vmcnt(3)" ::: "memory"); \
  __builtin_amdgcn_s_barrier();

#define RDA(KS) \
  _Pragma("unroll") for (int j = 0; j < 4; ++j) { \
    const int ra = wm * 64 + j * 16 + lg; \
    av[j] = *(const s16x8*)(sA + ra * 128 + (SWZ(4 * (KS) + hg, ra) << 4)); }

// ---------------------------------------------------------------- QKV GEMM, 128x384 tile
#define STG_A(DST, ORG, KT) \
  _Pragma("unroll") for (int rr = 0; rr < 2; ++rr) { \
    const int G = rr * 512 + tid; const int row = G >> 3, g = G & 7; \
    gld16((const char*)((ORG) + (size_t)row * 2048 + (size_t)(KT) * 64) + (SWZ(g, row) << 4), \
          (DST) + rr * 8192 + tid * 16); }

#define STG_B2(DST, ORG, KT, R0) \
  _Pragma("unroll") for (int rr = (R0); rr < (R0) + 2; ++rr) { \
    const int G = rr * 512 + tid; const int row = G >> 3, g = G & 7; \
    gld16((const char*)((ORG) + (size_t)row * 2048 + (size_t)(KT) * 64) + (SWZ(g, row) << 4), \
          (DST) + rr * 8192 + tid * 16); }

#define RDB(KS, CH) \
  _Pragma("unroll") for (int b = 0; b < 3; ++b) { \
    const int bb = (CH) * 3 + b; \
    const int cb = (bb >> 1) * 128 + wn * 16 + (bb & 1) * 64 + lg; \
    bv[b] = *(const s16x8*)(sB + cb * 128 + (SWZ(4 * (KS) + hg, cb) << 4)); }

#define MM12(CH) \
  _Pragma("unroll") for (int j = 0; j < 4; ++j) \
    _Pragma("unroll") for (int b = 0; b < 3; ++b) \
      acc[j][(CH) * 3 + b] = __builtin_amdgcn_mfma_f32_16x16x32_bf16( \
          av[j], bv[b], acc[j][(CH) * 3 + b], 0, 0, 0);

__global__ __launch_bounds__(512, 1) void gemm_qkv_384(
    const unsigned short* __restrict__ A,
    const unsigned short* __restrict__ Bt,
    const float* __restrict__ cosT, const float* __restrict__ sinT,
    unsigned short* __restrict__ qOut, unsigned short* __restrict__ kOut,
    unsigned short* __restrict__ vtOut)
{
  __shared__ char smem[131072];   // buf b: A @ b*65536 (16KB), B @ +16384 (48KB)
  const int tid = (int)threadIdx.x;
  const int wid = tid >> 6, l = tid & 63;
  const int lg = l & 15, hg = l >> 4;
  const int wm = wid >> 2, wn = wid & 3;
  const int s = ((int)blockIdx.x & 7) * 64 + ((int)blockIdx.x >> 3);
  const int bm0 = (s & 31) * 128, bn0 = (s >> 5) * 384;

  const unsigned short* Aorg = A + (size_t)bm0 * 2048;
  const unsigned short* Borg = Bt + (size_t)bn0 * 2048;

  f32x4 acc[4][6] = {};

  // prologue: all 8 loads of tile 0 (order A0,A1,B0..B5); first 5 must land
  STG_A(smem + 0, Aorg, 0)
  STG_B2(smem + 16384, Borg, 0, 0)
  STG_B2(smem + 16384, Borg, 0, 2)
  STG_B2(smem + 16384, Borg, 0, 4)
  asm volatile("s_waitcnt vmcnt(3)" ::: "memory");
  __builtin_amdgcn_s_barrier();

  for (int t = 0; t < 31; ++t) {
    const char* sA = smem + (t & 1) * 65536;
    const char* sB = sA + 16384;
    char* dA = smem + ((t & 1) ^ 1) * 65536;
    char* dB = dA + 16384;
    s16x8 av[4], bv[3];
    RDA(0) RDB(0, 0) STG_A(dA, Aorg, t + 1)      PH_PRE MM12(0) PH_POST_W2
    RDB(0, 1)        STG_B2(dB, Borg, t + 1, 0)  PH_PRE MM12(1) PH_POST_N
    RDA(1) RDB(1, 1) STG_B2(dB, Borg, t + 1, 2)  PH_PRE MM12(1) PH_POST_N
    RDB(1, 0)        STG_B2(dB, Borg, t + 1, 4)  PH_PRE MM12(0) PH_POST_W3
  }
  {  // tail tile t = 31 (buf 1), no issues; only full drain after phase 0
    const char* sA = smem + 65536;
    const char* sB = sA + 16384;
    s16x8 av[4], bv[3];
    RDA(0) RDB(0, 0)  PH_PRE MM12(0) PH_POST_W0
    RDB(0, 1)         PH_PRE MM12(1) PH_POST_N
    RDA(1) RDB(1, 1)  PH_PRE MM12(1) PH_POST_N
    RDB(1, 0)         PH_PRE MM12(0)
    __builtin_amdgcn_s_setprio(0);
  }

  // ---- epilogue: rotary for q/k head-groups, transposed-V for v head-groups
  #pragma unroll
  for (int j = 0; j < 4; ++j) {
    const int grow0 = bm0 + wm * 64 + j * 16 + hg * 4;
    const int b_ = grow0 >> 11;
    #pragma unroll
    for (int cg = 0; cg < 3; ++cg) {
      const int og = (bn0 >> 7) + cg;
      const int tt = og >> 4, h = og & 15;
      const int d = wn * 16 + lg;
      if (tt < 2) {
        unsigned short* dst = (tt == 0) ? qOut : kOut;
        #pragma unroll
        for (int r = 0; r < 4; ++r) {
          const int gr = grow0 + r;
          const int s1 = gr & 2047;
          const float x1 = acc[j][cg * 2 + 0][r];
          const float x2 = acc[j][cg * 2 + 1][r];
          const float cv = cosT[s1 * 64 + d];
          const float sv = sinT[s1 * 64 + d];
          const size_t base = (((size_t)b_ * 16 + h) * 2048 + s1) * 128;
          dst[base + d]      = f2bf(x1 * cv - x2 * sv);
          dst[base + d + 64] = f2bf(x2 * cv + x1 * sv);
        }
      } else {
        const int s0 = grow0 & 2047;
        s16x4 p1, p2;
        #pragma unroll
        for (int r = 0; r < 4; ++r) {
          p1[r] = (short)f2bf(acc[j][cg * 2 + 0][r]);
          p2[r] = (short)f2bf(acc[j][cg * 2 + 1][r]);
        }
        *(s16x4*)(vtOut + (((size_t)b_ * 16 + h) * 128 + d)      * 2048 + s0) = p1;
        *(s16x4*)(vtOut + (((size_t)b_ * 16 + h) * 128 + d + 64) * 2048 + s0) = p2;
      }
    }
  }
}

// ---------------------------------------------------------------- out-proj GEMM, 128x256
#define RDBO(KS, CH) \
  _Pragma("unroll") for (int b = 0; b < 2; ++b) { \
    const int cb = ((CH) * 2 + b) * 64 + wn * 16 + lg; \
    bv[b] = *(const s16x8*)(sB + cb * 128 + (SWZ(4 * (KS) + hg, cb) << 4)); }

#define MMO(CH) \
  _Pragma("unroll") for (int j = 0; j < 4; ++j) \
    _Pragma("unroll") for (int b = 0; b < 2; ++b) \
      acc[j][(CH) * 2 + b] = __builtin_amdgcn_mfma_f32_16x16x32_bf16( \
          av[j], bv[b], acc[j][(CH) * 2 + b], 0, 0, 0);

__global__ __launch_bounds__(512, 1) void gemm_op_256(
    const unsigned short* __restrict__ A,
    const unsigned short* __restrict__ Bt,
    float* __restrict__ C)
{
  __shared__ char smem[98304];   // buf b @ b*49152: A 16KB, B 32KB
  const int tid = (int)threadIdx.x;
  const int wid = tid >> 6, l = tid & 63;
  const int lg = l & 15, hg = l >> 4;
  const int wm = wid >> 2, wn = wid & 3;
  const int s = ((int)blockIdx.x & 7) * 32 + ((int)blockIdx.x >> 3);
  const int bm0 = (s & 31) * 128, bn0 = (s >> 5) * 256;

  const unsigned short* Aorg = A + (size_t)bm0 * 2048;
  const unsigned short* Borg = Bt + (size_t)bn0 * 2048;

  f32x4 acc[4][4] = {};

  STG_A(smem + 0, Aorg, 0)
  STG_B2(smem + 16384, Borg, 0, 0)
  STG_B2(smem + 16384, Borg, 0, 2)
  asm volatile("s_waitcnt vmcnt(2)" ::: "memory");
  __builtin_amdgcn_s_barrier();

  for (int t = 0; t < 31; ++t) {
    const char* sA = smem + (t & 1) * 49152;
    const char* sB = sA + 16384;
    char* dA = smem + ((t & 1) ^ 1) * 49152;
    char* dB = dA + 16384;
    s16x8 av[4], bv[2];
    RDA(0) RDBO(0, 0) STG_A(dA, Aorg, t + 1)      PH_PRE MMO(0) PH_POST_W2
    RDBO(0, 1)        STG_B2(dB, Borg, t + 1, 0)  PH_PRE MMO(1) PH_POST_N
    RDA(1) RDBO(1, 1) STG_B2(dB, Borg, t + 1, 2)  PH_PRE MMO(1) PH_POST_N
    RDBO(1, 0)                                    PH_PRE MMO(0) PH_POST_W2
  }
  {
    const char* sA = smem + 49152;
    const char* sB = sA + 16384;
    s16x8 av[4], bv[2];
    RDA(0) RDBO(0, 0)  PH_PRE MMO(0) PH_POST_W0
    RDBO(0, 1)         PH_PRE MMO(1) PH_POST_N
    RDA(1) RDBO(1, 1)  PH_PRE MMO(1) PH_POST_N
    RDBO(1, 0)         PH_PRE MMO(0)
    __builtin_amdgcn_s_setprio(0);
  }

  #pragma unroll
  for (int j = 0; j < 4; ++j) {
    const int row0 = bm0 + wm * 64 + j * 16 + hg * 4;
    #pragma unroll
    for (int b = 0; b < 4; ++b) {
      const int col = bn0 + b * 64 + wn * 16 + lg;
      #pragma unroll
      for (int r = 0; r < 4; ++r)
        C[(size_t)(row0 + r) * 2048 + col] = acc[j][b][r];
    }
  }
}

// ---------------------------------------------------------------- flash attention (r11)
// 32x32x16 MFMA. 512 blocks = 32 bh x 16 qt (paired j/15-j per CU -> 34 tiles/CU).
// 4 waves x 32 q-rows (QBLK=128). KV tiles 64, double-buffered, counted vmcnt(8).
// Lane owns q-row = l&31 in softmax space (S^T col). ONE state set per wave.
#define ASTG(BB, KV0) \
  _Pragma("unroll") for (int i = 0; i < 4; ++i) { \
    const int G = w * 256 + i * 64 + l; \
    const int rk = G >> 4, gk = G & 15; \
    gld16((const char*)(Kp + qkBase + (size_t)((KV0) + rk) * 128) + (SWZ4(gk, rk) << 4), \
          &sK[BB][w * 4096 + i * 1024]); \
    const int rv = G >> 3, gv = G & 7; \
    gld16((const char*)(Vt + qkBase + (size_t)rv * 2048 + (KV0)) + (SWZ(gv, rv) << 4), \
          &sV[BB][w * 4096 + i * 1024]); \
  }

__global__ __launch_bounds__(256) void attn_fwd(
    const unsigned short* __restrict__ Qp, const unsigned short* __restrict__ Kp,
    const unsigned short* __restrict__ Vt, unsigned short* __restrict__ AO)
{
  __shared__ char sK[2][16384];   // [64][256B] bf16, 16 granules/row, SWZ4
  __shared__ char sV[2][16384];   // [128][128B] bf16 (Vt tile), 8 granules/row, SWZ
  __shared__ char sP[16384];      // wave w: [32 q][64 kv] bf16 @ w*4096, SWZ

  const int tid = (int)threadIdx.x, w = tid >> 6, l = tid & 63;
  const int ql = l & 31, hg2 = l >> 5;
  const int bid = (int)blockIdx.x;
  const int p = bid >> 8, c = bid & 255;
  const int j = c >> 5, bh = c & 31;
  const int qt = p ? (15 - j) : j;               // CU pairing: 34 tiles/CU
  const size_t qkBase = (size_t)bh * 2048 * 128; // also Vt head base
  const int qw0 = qt * 128 + w * 32;
  const int qi = qw0 + ql;
  char* const pw = sP + w * 4096;

  // Q (B-operand): lane holds q-row ql, k = ks*16 + hg2*8 + 0..7
  s16x8 qf[8];
  #pragma unroll
  for (int ks = 0; ks < 8; ++ks)
    qf[ks] = *(const s16x8*)(Qp + qkBase + (size_t)(qw0 + ql) * 128 + ks * 16 + hg2 * 8);

  f32x16 ao[4] = {};
  float mrun = -1e30f, lrun = 0.f;
  const float SCALE = 0.08838834764831845f;   // 1/sqrt(128)
  const float L2E = 1.4426950408889634f;
  const float CS = SCALE * L2E;

  const int nkv = 2 * qt + 2;

  ASTG(0, 0)
  ASTG(1, 64)
  asm volatile("s_waitcnt vmcnt(8)" ::: "memory");   // tile 0 landed
  __builtin_amdgcn_s_barrier();

  for (int kv = 0; kv < nkv; ++kv) {
    const int cur = kv & 1;
    const int kv0 = kv * 64;
    const char* cK = sK[cur];
    const char* cV = sV[cur];
    const bool act = (kv0 <= qw0 + 31);   // wave-uniform

    if (act) {
      // ---- QK^T (swapped): S^T[kv][q], two 32-kv sub-blocks
      f32x16 sS0 = {}, sS1 = {};
      #pragma unroll
      for (int ks = 0; ks < 8; ++ks) {
        s16x8 k0 = *(const s16x8*)(cK + ql * 256 + (SWZ4(2 * ks + hg2, ql) << 4));
        s16x8 k1 = *(const s16x8*)(cK + (32 + ql) * 256 + (SWZ4(2 * ks + hg2, 32 + ql) << 4));
        sS0 = __builtin_amdgcn_mfma_f32_32x32x16_bf16(k0, qf[ks], sS0, 0, 0, 0);
        sS1 = __builtin_amdgcn_mfma_f32_32x32x16_bf16(k1, qf[ks], sS1, 0, 0, 0);
      }

      // ---- mask (diag tiles only) + row max
      const bool dg = (kv0 + 63 > qw0);
      if (dg) {
        #pragma unroll
        for (int r = 0; r < 16; ++r) {
          const int jl = (r & 3) + 8 * (r >> 2) + 4 * hg2;
          if (kv0 + jl > qi)      sS0[r] = -1e30f;
          if (kv0 + 32 + jl > qi) sS1[r] = -1e30f;
        }
      }
      float mt = -1e30f;
      #pragma unroll
      for (int r = 0; r < 16; ++r) {
        mt = fmaxf(mt, sS0[r]);
        mt = fmaxf(mt, sS1[r]);
      }
      mt = fmaxf(mt, __shfl_xor(mt, 32));
      mt *= SCALE;
      if (!__all(mt - mrun <= 8.0f)) {
        const float mnew = fmaxf(mrun, mt);
        const float alpha = exp2f((mrun - mnew) * L2E);
        #pragma unroll
        for (int r = 0; r < 16; ++r) {
          const float ar = __shfl(alpha, (r & 3) + 8 * (r >> 2) + 4 * hg2);
          ao[0][r] *= ar; ao[1][r] *= ar; ao[2][r] *= ar; ao[3][r] *= ar;
        }
        lrun *= alpha;
        mrun = mnew;
      }
      const float mL = mrun * L2E;
      float ls = 0.f;
      // exp + P-write: reg r -> kv_local = (r&3) + 8*(r>>2) + 4*hg2 (+32 for sub1)
      #pragma unroll
      for (int rq = 0; rq < 4; ++rq) {
        s16x4 pk0, pk1;
        #pragma unroll
        for (int i = 0; i < 4; ++i) {
          const float e0 = exp2f(sS0[rq * 4 + i] * CS - mL); ls += e0; pk0[i] = (short)f2bf(e0);
          const float e1 = exp2f(sS1[rq * 4 + i] * CS - mL); ls += e1; pk1[i] = (short)f2bf(e1);
        }
        *(s16x4*)(pw + ql * 128 + (SWZ(rq, ql) << 4) + hg2 * 8) = pk0;
        *(s16x4*)(pw + ql * 128 + (SWZ(4 + rq, ql) << 4) + hg2 * 8) = pk1;
      }
      ls += __shfl_xor(ls, 32);
      lrun += ls;
      asm volatile("" ::: "memory");   // P writes precede P reads (in-order DS)

      // ---- PV: O[q][d] += P[q][kv] * Vt[d][kv]
      s16x8 pf[4];
      #pragma unroll
      for (int ks2 = 0; ks2 < 4; ++ks2)
        pf[ks2] = *(const s16x8*)(pw + ql * 128 + (SWZ(2 * ks2 + hg2, ql) << 4));
      #pragma unroll
      for (int db = 0; db < 4; ++db) {
        const int vr = db * 32 + ql;
        #pragma unroll
        for (int ks2 = 0; ks2 < 4; ++ks2) {
          s16x8 vf = *(const s16x8*)(cV + vr * 128 + (SWZ(2 * ks2 + hg2, vr) << 4));
          ao[db] = __builtin_amdgcn_mfma_f32_32x32x16_bf16(pf[ks2], vf, ao[db], 0, 0, 0);
        }
      }
    }

    // ---- advance pipeline (block-uniform)
    asm volatile("s_waitcnt lgkmcnt(0)" ::: "memory");
    __builtin_amdgcn_s_barrier();                    // all waves done reading buf[cur]
    if (kv + 2 < nkv) {
      ASTG(cur, kv0 + 128)                           // refill buf[cur] with tile kv+2
      asm volatile("s_waitcnt vmcnt(8)" ::: "memory");  // tile kv+1 landed
    } else {
      asm volatile("s_waitcnt vmcnt(0)" ::: "memory");
    }
    __builtin_amdgcn_s_barrier();
  }

  // ---- normalize + store AO[b*2048+s][h*128+d] bf16
  float li[16];
  #pragma unroll
  for (int r = 0; r < 16; ++r)
    li[r] = 1.0f / __shfl(lrun, (r & 3) + 8 * (r >> 2) + 4 * hg2);
  const int b = bh >> 4, h = bh & 15;
  #pragma unroll
  for (int db = 0; db < 4; ++db) {
    const int d = h * 128 + db * 32 + ql;
    #pragma unroll
    for (int r = 0; r < 16; ++r) {
      const int q = qw0 + (r & 3) + 8 * (r >> 2) + 4 * hg2;
      AO[((size_t)(b * 2048 + q)) * 2048 + d] = f2bf(ao[db][r] * li[r]);
    }
  }
}

// ---------------------------------------------------------------- launch
extern "C" void kernel_launch(void* const* d_in, const int* in_sizes, int n_in,
                              void* d_out, int out_size, void* d_ws, size_t ws_size,
                              hipStream_t stream) {
  const float* x    = (const float*)d_in[0];
  const float* qkvw = (const float*)d_in[1];
  const float* ow   = (const float*)d_in[2];
  const float* cosT = (const float*)d_in[3];
  const float* sinT = (const float*)d_in[4];
  float* out = (float*)d_out;

  unsigned short* X16  = (unsigned short*)d_ws;        // 4096x2048
  unsigned short* W16  = X16  + (size_t)8388608;       // 6144x2048
  unsigned short* OW16 = W16  + (size_t)12582912;      // 2048x2048
  unsigned short* Qp   = OW16 + (size_t)4194304;       // [2][16][2048][128]
  unsigned short* Kp   = Qp   + (size_t)8388608;
  unsigned short* Vtp  = Kp   + (size_t)8388608;       // [2][16][128][2048]
  unsigned short* AO   = Vtp  + (size_t)8388608;       // 4096x2048

  cvt_all<<<24576, 256, 0, stream>>>(x, qkvw, ow, X16, W16, OW16);

  gemm_qkv_384<<<512, 512, 0, stream>>>(X16, W16, cosT, sinT, Qp, Kp, Vtp);

  attn_fwd<<<512, 256, 0, stream>>>(Qp, Kp, Vtp, AO);

  gemm_op_256<<<256, 512, 0, stream>>>(AO, OW16, out);
}